// Round 4
// baseline (146.809 us; speedup 1.0000x reference)
//
#include <hip/hip_runtime.h>
#include <hip/hip_bf16.h>

typedef __attribute__((ext_vector_type(8))) short bf16x8;
typedef __attribute__((ext_vector_type(4))) float f32x4;

#define BAND 24576   // one X band buffer: [slot4][row6][col64][16B]

// ---------------- weight synthesis: softmax(alphas) + circulant averages ----
__global__ void wsynth_kernel(const float* __restrict__ W,
                              const float* __restrict__ alphas,
                              const float* __restrict__ gumbels,
                              __hip_bfloat16* __restrict__ Wr) {
    int tid = blockIdx.x * 256 + threadIdx.x;   // 65536 threads: one per (o,i)
    int o = tid >> 8, i = tid & 255;

    float a[7]; float mx = -1e30f;
    for (int j = 0; j < 7; ++j) { a[j] = alphas[j] + 1.0e-4f * gumbels[j]; mx = fmaxf(mx, a[j]); }
    float s = 0.f;
    for (int j = 0; j < 7; ++j) { a[j] = __expf(a[j] - mx); s += a[j]; }
    float invs = 1.0f / s;
    for (int j = 0; j < 7; ++j) a[j] *= invs;

    float acc[9];
    const float* w0 = W + ((size_t)(o * 256 + i)) * 9;
    for (int t = 0; t < 9; ++t) acc[t] = a[0] * w0[t];

    for (int idx = 1; idx < 7; ++idx) {
        int b = 1 << idx;
        int r = o & (b - 1), sc = i & (b - 1);
        int d = (sc - r) & (b - 1);
        int qb = o - r, pb = i - sc;
        float sum[9];
        for (int t = 0; t < 9; ++t) sum[t] = 0.f;
        for (int t = 0; t < b; ++t) {
            const float* wp = W + ((size_t)((qb + t) * 256 + pb + ((t + d) & (b - 1)))) * 9;
            #pragma unroll
            for (int tp = 0; tp < 9; ++tp) sum[tp] += wp[tp];
        }
        float sc2 = a[idx] / (float)b;
        for (int tp = 0; tp < 9; ++tp) acc[tp] += sc2 * sum[tp];
    }
    // layout [tap][o][c] so conv A-operand k (=c) is contiguous
    for (int tp = 0; tp < 9; ++tp)
        Wr[((size_t)(tp * 256 + o)) * 256 + i] = __float2bfloat16(acc[tp]);
}

// ---------------- conv helpers ----------------------------------------------
union BFPack { short s[8]; bf16x8 v; };

__device__ __forceinline__ bf16x8 pack8(const float* f) {
    BFPack p;
    #pragma unroll
    for (int j = 0; j < 8; ++j) {
        __hip_bfloat16 h = __float2bfloat16(f[j]);
        p.s[j] = *reinterpret_cast<short*>(&h);
    }
    return p.v;
}

// load one band (6 rows x 64 cols x 32 ch) worth of this thread's share from
// fp32 NCHW, border-zeroed, converted to bf16 in-register.
__device__ __forceinline__ void stage_load(const float* __restrict__ xb, int ch0, int y0,
                                           int g, int px, bf16x8 (&sv)[3]) {
    #pragma unroll
    for (int rr = 0; rr < 3; ++rr) {
        int pxt = px + rr * 128;
        int row = y0 - 1 + (pxt >> 6);
        int col = (pxt & 63) - 1;
        bool ok = ((unsigned)row < 56u) && ((unsigned)col < 56u);
        int rowc = row < 0 ? 0 : (row > 55 ? 55 : row);
        int colc = col < 0 ? 0 : (col > 55 ? 55 : col);
        const float* p = xb + (size_t)(ch0 + g * 8) * 3136 + rowc * 56 + colc;
        float tmp[8];
        #pragma unroll
        for (int j = 0; j < 8; ++j) {
            float v = p[(size_t)j * 3136];
            tmp[j] = ok ? v : 0.f;
        }
        sv[rr] = pack8(tmp);
    }
}

__device__ __forceinline__ void stage_write(char* dst, int g, int px, const bf16x8 (&sv)[3]) {
    #pragma unroll
    for (int rr = 0; rr < 3; ++rr)
        *reinterpret_cast<bf16x8*>(dst + g * 6144 + (px + rr * 128) * 16) = sv[rr];
}

// ---------------- chunk pair: 18 tap-steps, 2 barriers, reg read-ahead ------
template<bool LAST>
__device__ __forceinline__ void chunk_pair(
    int cp, char* smem, const float* __restrict__ xb,
    const __hip_bfloat16* const (&aPtr)[4],
    const int (&bOff)[7], int y0, int g, int px,
    bf16x8 (&afr)[2][4], bf16x8 (&bfA)[2][4],
    f32x4 (&acc)[4][7])
{
    const int cp64 = cp * 64;          // element offset of chunk 2cp in a W row
    #pragma unroll
    for (int u = 0; u < 2; ++u) {
        bf16x8 sv[3];
        #pragma unroll
        for (int r = 0; r < 9; ++r) {
            const int cur = (u + r) & 1, nxt = cur ^ 1;
            const int dy = r / 3 - 1, dx = r % 3 - 1;
            const int timm = (dy * 64 + dx) * 16;
            const char* bandCur = smem + u * BAND;

            // prefetch frags for step kk+1 (af: global L2; bfA: LDS)
            if (!(LAST && u == 1 && r == 8)) {
                const int tapn = (r == 8) ? 0 : r + 1;
                const int eoff = tapn * 65536 + (u + (r == 8 ? 1 : 0)) * 32;
                #pragma unroll
                for (int nf = 0; nf < 4; ++nf)
                    afr[nxt][nf] = *(const bf16x8*)(aPtr[nf] + cp64 + eoff);
                const int dyn = tapn / 3 - 1, dxn = tapn % 3 - 1;
                const int timn = (dyn * 64 + dxn) * 16;
                const char* bandN = smem + ((r == 8) ? (u ^ 1) : u) * BAND;
                #pragma unroll
                for (int mf = 0; mf < 4; ++mf)
                    bfA[nxt][mf] = *(const bf16x8*)(bandN + bOff[mf] + timn);
            }
            // JIT read of this step's remaining 3 pixel frags (covered by 16 MFMAs)
            bf16x8 bfB[3];
            #pragma unroll
            for (int mf = 0; mf < 3; ++mf)
                bfB[mf] = *(const bf16x8*)(bandCur + bOff[4 + mf] + timm);

            // issue next band's global loads early (chunk c+1)
            if (r == 0 && !(LAST && u == 1))
                stage_load(xb, (2 * cp + u + 1) * 32, y0, g, px, sv);

            __builtin_amdgcn_s_setprio(1);
            #pragma unroll
            for (int nf = 0; nf < 4; ++nf)
                #pragma unroll
                for (int mf = 0; mf < 4; ++mf)
                    acc[nf][mf] = __builtin_amdgcn_mfma_f32_16x16x32_bf16(
                        afr[cur][nf], bfA[cur][mf], acc[nf][mf], 0, 0, 0);
            #pragma unroll
            for (int nf = 0; nf < 4; ++nf)
                #pragma unroll
                for (int mf = 0; mf < 3; ++mf)
                    acc[nf][4 + mf] = __builtin_amdgcn_mfma_f32_16x16x32_bf16(
                        afr[cur][nf], bfB[mf], acc[nf][4 + mf], 0, 0, 0);
            __builtin_amdgcn_s_setprio(0);

            // write next band into the other buffer (overwritten one is 2 chunks old)
            if (r == 6 && !(LAST && u == 1))
                stage_write(smem + (u ^ 1) * BAND, g, px, sv);
            // single barrier per chunk: band(c+1) complete & all waves past band(c-1)
            if (r == 7 && !(LAST && u == 1))
                __syncthreads();
        }
    }
}

__global__ __launch_bounds__(512, 2) void conv_kernel(
        const float* __restrict__ x,
        const __hip_bfloat16* __restrict__ Wr,
        float* __restrict__ out) {
    __shared__ char smem[2 * BAND];

    const int tid = threadIdx.x;
    const int w = tid >> 6, lane = tid & 63, l15 = lane & 15, q = lane >> 4;
    const int bid = blockIdx.x;            // 224 blocks: 14 per image, 4 rows each
    const int bimg = bid / 14;
    const int y0 = (bid - bimg * 14) * 4;

    const int wn = (w & 3) << 6;           // wave och base (4 waves x 64)
    const int wm = (w >> 2) * 112;         // wave pixel base (2 waves x 112)
    const int g = tid >> 7, px = tid & 127;

    const float* xb = x + (size_t)bimg * 256 * 3136;

    const __hip_bfloat16* aPtr[4];
    #pragma unroll
    for (int nf = 0; nf < 4; ++nf)
        aPtr[nf] = Wr + (wn + nf * 16 + l15) * 256 + q * 8;

    int bOff[7];
    #pragma unroll
    for (int mf = 0; mf < 7; ++mf) {
        int p = wm + mf * 16 + l15;            // local pixel 0..223
        int y = p / 56, xx = p - y * 56;
        bOff[mf] = q * 6144 + ((y + 1) * 64 + (xx + 1)) * 16;
    }

    f32x4 acc[4][7];
    #pragma unroll
    for (int a1 = 0; a1 < 4; ++a1)
        #pragma unroll
        for (int a2 = 0; a2 < 7; ++a2)
            acc[a1][a2] = (f32x4){0.f, 0.f, 0.f, 0.f};

    bf16x8 afr[2][4], bfA[2][4];

    // prologue: stage band 0, then read frags(0) into set 0
    {
        bf16x8 sv[3];
        stage_load(xb, 0, y0, g, px, sv);
        stage_write(smem, g, px, sv);
    }
    __syncthreads();
    {
        const int timm = (-64 - 1) * 16;       // tap 0: dy=-1, dx=-1
        #pragma unroll
        for (int nf = 0; nf < 4; ++nf) afr[0][nf] = *(const bf16x8*)(aPtr[nf]);
        #pragma unroll
        for (int mf = 0; mf < 4; ++mf) bfA[0][mf] = *(const bf16x8*)(smem + bOff[mf] + timm);
    }

    for (int cp = 0; cp < 3; ++cp)
        chunk_pair<false>(cp, smem, xb, aPtr, bOff, y0, g, px, afr, bfA, acc);
    chunk_pair<true>(3, smem, xb, aPtr, bOff, y0, g, px, afr, bfA, acc);

    // epilogue: och from (q,nf,rr), pixel from (wm,mf,l15)
    const int nb = wn + q * 4;
    const size_t obB = (size_t)bimg * 256 * 3136;
    #pragma unroll
    for (int mf = 0; mf < 7; ++mf) {
        int pm = y0 * 56 + wm + mf * 16 + l15;
        #pragma unroll
        for (int nf = 0; nf < 4; ++nf) {
            #pragma unroll
            for (int rr = 0; rr < 4; ++rr)
                out[obB + (size_t)(nb + nf * 16 + rr) * 3136 + pm] = acc[nf][mf][rr];
        }
    }
}

extern "C" void kernel_launch(void* const* d_in, const int* in_sizes, int n_in,
                              void* d_out, int out_size, void* d_ws, size_t ws_size,
                              hipStream_t stream) {
    const float* x       = (const float*)d_in[0];
    const float* weight  = (const float*)d_in[1];
    const float* alphas  = (const float*)d_in[2];
    const float* gumbels = (const float*)d_in[3];
    float* out = (float*)d_out;

    __hip_bfloat16* Wr = (__hip_bfloat16*)d_ws;   // 9*256*256 bf16 = 1.125 MB

    hipLaunchKernelGGL(wsynth_kernel, dim3(256), dim3(256), 0, stream,
                       weight, alphas, gumbels, Wr);
    hipLaunchKernelGGL(conv_kernel,   dim3(224), dim3(512), 0, stream,
                       x, Wr, out);
}